// Round 6
// baseline (182.390 us; speedup 1.0000x reference)
//
#include <hip/hip_runtime.h>
#include <hip/hip_bf16.h>

typedef unsigned short u16;
typedef __attribute__((ext_vector_type(8))) __bf16 bf16x8;
typedef __attribute__((ext_vector_type(4))) float f32x4;

__device__ __forceinline__ u16 f2bf(float f) {
    unsigned u = __builtin_bit_cast(unsigned, f);
    u += 0x7FFFu + ((u >> 16) & 1u);
    return (u16)(u >> 16);
}
__device__ __forceinline__ float bf2f(u16 v) {
    unsigned u = ((unsigned)v) << 16;
    return __builtin_bit_cast(float, u);
}

// ------------------------------------------------------------ qkv + edge ---
// grid 512, self-contained (no prep pass):
//  bid<256:  qkv  — stage x-tile transposed + W(bf16) in LDS, 24 MFMAs
//  bid>=256: edge — stage 3 x-rows (zero-padded) + We1 reorder in LDS, 36 MFMAs
__global__ __launch_bounds__(256) void qkv_edge_kernel(
    const float* __restrict__ x,
    const float* __restrict__ Wq, const float* __restrict__ bq,
    const float* __restrict__ Wk, const float* __restrict__ bk,
    const float* __restrict__ Wv, const float* __restrict__ bv,
    const float* __restrict__ We1, const float* __restrict__ be1,
    const float* __restrict__ bn_w, const float* __restrict__ bn_b,
    const float* __restrict__ bn_mean, const float* __restrict__ bn_var,
    const float* __restrict__ We2, const float* __restrict__ be2,
    const float* __restrict__ beta,
    u16* __restrict__ Qt, u16* __restrict__ Kt, u16* __restrict__ Vm,
    float* __restrict__ wkey)
{
    __shared__ __align__(16) u16 sm[33280];   // 65 KB, partitioned per branch
    const int t = threadIdx.x;
    const int wv = t >> 6, lane = t & 63;
    const int quad = lane >> 4, l15 = lane & 15;

    if (blockIdx.x < 256) {
        // ---------------- qkv ----------------
        u16* Wl   = sm;                 // [3][64][72]  = 13824 u16
        u16* xt_s = sm + 13824;         // [64][66]     =  4224 u16
        u16* vt   = sm + 13824 + 4224;  // [64][72]     =  4608 u16
        const int b = blockIdx.x >> 6;
        const int n0 = (blockIdx.x & 63) << 6;

        const float* Wmat[3] = {Wq, Wk, Wv};
#pragma unroll
        for (int m = 0; m < 3; ++m)
            for (int i = 0; i < 16; ++i) {
                int lin = t + i * 256;
                Wl[(m * 64 + (lin >> 6)) * 72 + (lin & 63)] = f2bf(Wmat[m][lin]);
            }
        for (int i = 0; i < 16; ++i) {
            int lin = t + i * 256;
            int c = lin >> 6, nn = lin & 63;
            xt_s[nn * 66 + c] = f2bf(x[(size_t)(b * 64 + c) * 4096 + n0 + nn]);
        }
        __syncthreads();

        bf16x8 bx[2];
#pragma unroll
        for (int h = 0; h < 2; ++h)
            bx[h] = *reinterpret_cast<const bf16x8*>(
                &xt_s[(wv * 16 + l15) * 66 + h * 32 + quad * 8]);

        f32x4 d[3][4];
#pragma unroll
        for (int m = 0; m < 3; ++m)
#pragma unroll
            for (int mt = 0; mt < 4; ++mt) d[m][mt] = (f32x4){0.f, 0.f, 0.f, 0.f};

#pragma unroll
        for (int h = 0; h < 2; ++h)
#pragma unroll
            for (int m = 0; m < 3; ++m)
#pragma unroll
                for (int mt = 0; mt < 4; ++mt) {
                    bf16x8 af = *reinterpret_cast<const bf16x8*>(
                        &Wl[(m * 64 + mt * 16 + l15) * 72 + h * 32 + quad * 8]);
                    d[m][mt] = __builtin_amdgcn_mfma_f32_16x16x32_bf16(af, bx[h], d[m][mt], 0, 0, 0);
                }

        const float* bias[3] = {bq, bk, bv};
#pragma unroll
        for (int m = 0; m < 3; ++m)
#pragma unroll
            for (int mt = 0; mt < 4; ++mt) {
                float4 bi = *reinterpret_cast<const float4*>(bias[m] + mt * 16 + quad * 4);
                d[m][mt][0] += bi.x; d[m][mt][1] += bi.y; d[m][mt][2] += bi.z; d[m][mt][3] += bi.w;
            }

        const int px = n0 + wv * 16 + l15;
#pragma unroll
        for (int m = 0; m < 2; ++m) {
            u16* dst = (m == 0 ? Qt : Kt) + ((size_t)(b * 4096 + px)) * 64;
#pragma unroll
            for (int mt = 0; mt < 4; ++mt) {
                uint2 pk;
                pk.x = (unsigned)f2bf(d[m][mt][0]) | ((unsigned)f2bf(d[m][mt][1]) << 16);
                pk.y = (unsigned)f2bf(d[m][mt][2]) | ((unsigned)f2bf(d[m][mt][3]) << 16);
                *reinterpret_cast<uint2*>(dst + mt * 16 + quad * 4) = pk;
            }
        }
#pragma unroll
        for (int mt = 0; mt < 4; ++mt)
#pragma unroll
            for (int r = 0; r < 4; ++r)
                vt[(mt * 16 + quad * 4 + r) * 72 + wv * 16 + l15] = f2bf(d[2][mt][r]);
        __syncthreads();
        {
            const int oc = t >> 2, chk = t & 3;
            u16 tmp[16];
#pragma unroll
            for (int j = 0; j < 16; ++j) tmp[j] = vt[oc * 72 + chk * 16 + j];
            u16* dst = Vm + (size_t)(b * 64 + oc) * 4096 + n0 + chk * 16;
            *reinterpret_cast<uint4*>(dst)     = *reinterpret_cast<const uint4*>(&tmp[0]);
            *reinterpret_cast<uint4*>(dst + 8) = *reinterpret_cast<const uint4*>(&tmp[8]);
        }
    } else {
        // ---------------- edge ----------------
        u16* Ae_s = sm;            // [32][584]     = 18688 u16 (row pad vs 576)
        u16* xr_s = sm + 18688;    // [3][66][72]   = 14256 u16 (col 0/65 zero)
        const int eb = blockIdx.x - 256;
        const int b = eb >> 6, h = eb & 63;

        if (t < 192) {
            int kh = t / 64, rem = t & 63;
            int col = (rem >> 5) * 65, ci2 = (rem & 31) * 2;
            *reinterpret_cast<unsigned*>(&xr_s[(kh * 66 + col) * 72 + ci2]) = 0u;
        }
#pragma unroll
        for (int i = 0; i < 8; ++i) {
            int pr = t + i * 256;
            int ch = pr >> 6, ci = pr & 63;
            const float* src = We1 + ch * 576 + ci * 9;
#pragma unroll
            for (int p = 0; p < 9; ++p)
                Ae_s[ch * 584 + p * 64 + ci] = f2bf(src[p]);
        }
#pragma unroll
        for (int i = 0; i < 48; ++i) {
            int e = t + i * 256;
            int kh = e >> 12, rem = e & 4095;
            int ci = rem >> 6, w = rem & 63;
            int hs = h + kh - 1;
            float v = 0.f;
            if ((unsigned)hs < 64u)
                v = x[((size_t)(b * 64 + ci) * 64 + hs) * 64 + w];
            xr_s[(kh * 66 + w + 1) * 72 + ci] = f2bf(v);
        }
        __syncthreads();

        f32x4 e[2];
        e[0] = (f32x4){0.f, 0.f, 0.f, 0.f};
        e[1] = (f32x4){0.f, 0.f, 0.f, 0.f};
#pragma unroll
        for (int p = 0; p < 9; ++p) {
            const int kh = p / 3, kw = p - kh * 3;
#pragma unroll
            for (int half = 0; half < 2; ++half) {
                bf16x8 bfr = *reinterpret_cast<const bf16x8*>(
                    &xr_s[(kh * 66 + wv * 16 + l15 + kw) * 72 + half * 32 + quad * 8]);
#pragma unroll
                for (int mt = 0; mt < 2; ++mt) {
                    bf16x8 af = *reinterpret_cast<const bf16x8*>(
                        &Ae_s[(mt * 16 + l15) * 584 + p * 64 + half * 32 + quad * 8]);
                    e[mt] = __builtin_amdgcn_mfma_f32_16x16x32_bf16(af, bfr, e[mt], 0, 0, 0);
                }
            }
        }
        float partial = 0.f;
#pragma unroll
        for (int mt = 0; mt < 2; ++mt) {
            float4 bw = *reinterpret_cast<const float4*>(bn_w    + mt * 16 + quad * 4);
            float4 bb = *reinterpret_cast<const float4*>(bn_b    + mt * 16 + quad * 4);
            float4 bm = *reinterpret_cast<const float4*>(bn_mean + mt * 16 + quad * 4);
            float4 bv2 = *reinterpret_cast<const float4*>(bn_var + mt * 16 + quad * 4);
            float4 b1 = *reinterpret_cast<const float4*>(be1     + mt * 16 + quad * 4);
            float4 w2 = *reinterpret_cast<const float4*>(We2     + mt * 16 + quad * 4);
            float sc, sh;
            sc = bw.x * rsqrtf(bv2.x + 1e-5f); sh = (b1.x - bm.x) * sc + bb.x;
            partial += fmaxf(e[mt][0] * sc + sh, 0.f) * w2.x;
            sc = bw.y * rsqrtf(bv2.y + 1e-5f); sh = (b1.y - bm.y) * sc + bb.y;
            partial += fmaxf(e[mt][1] * sc + sh, 0.f) * w2.y;
            sc = bw.z * rsqrtf(bv2.z + 1e-5f); sh = (b1.z - bm.z) * sc + bb.z;
            partial += fmaxf(e[mt][2] * sc + sh, 0.f) * w2.z;
            sc = bw.w * rsqrtf(bv2.w + 1e-5f); sh = (b1.w - bm.w) * sc + bb.w;
            partial += fmaxf(e[mt][3] * sc + sh, 0.f) * w2.w;
        }
        partial += __shfl_xor(partial, 16);
        partial += __shfl_xor(partial, 32);
        if (lane < 16) {
            float s = partial + be2[0];
            float sg = 1.f / (1.f + __expf(-s));
            wkey[(size_t)b * 4096 + h * 64 + wv * 16 + lane] = 1.f + beta[0] * sg;
        }
    }
}

// ------------------------------------------------------------- attention ---
// grid 256*NSPLIT; 128 thr = 2 waves x 32 q rows (2 independent 16-row chains).
// NSPLIT=8 -> 4096 waves = 16 waves/CU. S^T = K*Q^T, fixed-offset softmax,
// P via wave-local LDS, O += P*V^T, bf16 O_part epilogue. No barriers in k-loop.
template <int NSPLIT>
__global__ __launch_bounds__(128, 4) void attn_kernel(
    const u16* __restrict__ Qt, const u16* __restrict__ Kt,
    const u16* __restrict__ Vm, const float* __restrict__ wkey,
    u16* __restrict__ O_part, float* __restrict__ l_part)
{
    constexpr int KT_ITERS = 64 / NSPLIT;
    __shared__ __align__(16) u16 p_s_all[2 * 32 * 68];
    const int t = threadIdx.x;
    const int qi = blockIdx.x / NSPLIT;        // 0..255 (64-row q block)
    const int split = blockIdx.x % NSPLIT;
    const int b = qi >> 6;
    const int n0 = (qi & 63) << 6;
    const int wv = t >> 6, lane = t & 63;
    const int quad = lane >> 4, l15 = lane & 15;
    u16* p_s = p_s_all + wv * (32 * 68);

    const u16* Qb = Qt + (size_t)b * 4096 * 64;
    const u16* Kb = Kt + (size_t)b * 4096 * 64;
    const u16* Vb = Vm + (size_t)b * 64 * 4096;
    const float* wb = wkey + (size_t)b * 4096;

    bf16x8 qf[2][2];
#pragma unroll
    for (int nt = 0; nt < 2; ++nt)
#pragma unroll
        for (int h = 0; h < 2; ++h)
            qf[nt][h] = __builtin_bit_cast(bf16x8, *reinterpret_cast<const uint4*>(
                Qb + (size_t)(n0 + wv * 32 + nt * 16 + l15) * 64 + h * 32 + quad * 8));

    const int kt0 = split * KT_ITERS;
    uint4 kf[4][2];
    float4 wf[4];
#pragma unroll
    for (int mt = 0; mt < 4; ++mt) {
#pragma unroll
        for (int h = 0; h < 2; ++h)
            kf[mt][h] = *reinterpret_cast<const uint4*>(
                Kb + (size_t)(kt0 * 64 + mt * 16 + l15) * 64 + h * 32 + quad * 8);
        wf[mt] = *reinterpret_cast<const float4*>(wb + kt0 * 64 + mt * 16 + quad * 4);
    }

    f32x4 o[2][4];
#pragma unroll
    for (int m2 = 0; m2 < 2; ++m2)
#pragma unroll
        for (int f = 0; f < 4; ++f) o[m2][f] = (f32x4){0.f, 0.f, 0.f, 0.f};
    float l_acc[2] = {0.f, 0.f};

    for (int kt = kt0; kt < kt0 + KT_ITERS; ++kt) {
        uint4 vf[4][2];
#pragma unroll
        for (int f = 0; f < 4; ++f)
#pragma unroll
            for (int h = 0; h < 2; ++h)
                vf[f][h] = *reinterpret_cast<const uint4*>(
                    Vb + (size_t)(f * 16 + l15) * 4096 + kt * 64 + h * 32 + quad * 8);

        f32x4 s[4][2];
#pragma unroll
        for (int mt = 0; mt < 4; ++mt)
#pragma unroll
            for (int nt = 0; nt < 2; ++nt) {
                f32x4 a = (f32x4){0.f, 0.f, 0.f, 0.f};
                a = __builtin_amdgcn_mfma_f32_16x16x32_bf16(
                        __builtin_bit_cast(bf16x8, kf[mt][0]), qf[nt][0], a, 0, 0, 0);
                a = __builtin_amdgcn_mfma_f32_16x16x32_bf16(
                        __builtin_bit_cast(bf16x8, kf[mt][1]), qf[nt][1], a, 0, 0, 0);
                s[mt][nt] = a;
            }

        const int ktn = (kt + 1 < kt0 + KT_ITERS) ? kt + 1 : kt0;
#pragma unroll
        for (int mt = 0; mt < 4; ++mt)
#pragma unroll
            for (int h = 0; h < 2; ++h)
                kf[mt][h] = *reinterpret_cast<const uint4*>(
                    Kb + (size_t)(ktn * 64 + mt * 16 + l15) * 64 + h * 32 + quad * 8);

#pragma unroll
        for (int mt = 0; mt < 4; ++mt)
#pragma unroll
            for (int nt = 0; nt < 2; ++nt) {
                u16 pk[4];
#pragma unroll
                for (int r = 0; r < 4; ++r) {
                    float p = __expf(s[mt][nt][r] - 12.0f) *
                              reinterpret_cast<const float*>(&wf[mt])[r];
                    l_acc[nt] += p;
                    pk[r] = f2bf(p);
                }
                uint2 packed;
                packed.x = (unsigned)pk[0] | ((unsigned)pk[1] << 16);
                packed.y = (unsigned)pk[2] | ((unsigned)pk[3] << 16);
                *reinterpret_cast<uint2*>(
                    &p_s[(nt * 16 + l15) * 68 + mt * 16 + quad * 4]) = packed;
            }

#pragma unroll
        for (int mt = 0; mt < 4; ++mt)
            wf[mt] = *reinterpret_cast<const float4*>(wb + ktn * 64 + mt * 16 + quad * 4);

        bf16x8 pa[2][2];
#pragma unroll
        for (int m2 = 0; m2 < 2; ++m2)
#pragma unroll
            for (int h = 0; h < 2; ++h) {
                uint2 lo = *reinterpret_cast<const uint2*>(
                    &p_s[(m2 * 16 + l15) * 68 + h * 32 + quad * 8]);
                uint2 hi = *reinterpret_cast<const uint2*>(
                    &p_s[(m2 * 16 + l15) * 68 + h * 32 + quad * 8 + 4]);
                uint4 c4; c4.x = lo.x; c4.y = lo.y; c4.z = hi.x; c4.w = hi.y;
                pa[m2][h] = __builtin_bit_cast(bf16x8, c4);
            }

#pragma unroll
        for (int m2 = 0; m2 < 2; ++m2)
#pragma unroll
            for (int f = 0; f < 4; ++f) {
                o[m2][f] = __builtin_amdgcn_mfma_f32_16x16x32_bf16(
                    pa[m2][0], __builtin_bit_cast(bf16x8, vf[f][0]), o[m2][f], 0, 0, 0);
                o[m2][f] = __builtin_amdgcn_mfma_f32_16x16x32_bf16(
                    pa[m2][1], __builtin_bit_cast(bf16x8, vf[f][1]), o[m2][f], 0, 0, 0);
            }
    }

    const size_t pbase = (size_t)blockIdx.x * 64;
#pragma unroll
    for (int nt = 0; nt < 2; ++nt) {
        float v = l_acc[nt];
        v += __shfl_xor(v, 16);
        v += __shfl_xor(v, 32);
        if (lane < 16) l_part[pbase + wv * 32 + nt * 16 + lane] = v;
    }
#pragma unroll
    for (int m2 = 0; m2 < 2; ++m2)
#pragma unroll
        for (int f = 0; f < 4; ++f)
#pragma unroll
            for (int r = 0; r < 4; ++r)
                O_part[(pbase + wv * 32 + m2 * 16 + quad * 4 + r) * 64 + f * 16 + l15] =
                    f2bf(o[m2][f][r]);
}

// ---------------------------------------------------------------- combine --
// grid 1024: 16 q-rows per block (4 blocks/CU). Sum NSPLIT partials,
// normalize, gamma*O + x, transpose (n,c)->(c,n).
template <int NSPLIT>
__global__ __launch_bounds__(256) void combine_kernel(
    const u16* __restrict__ O_part, const float* __restrict__ l_part,
    const float* __restrict__ x, const float* __restrict__ g_gamma,
    float* __restrict__ out)
{
    __shared__ float ot[16 * 65];
    __shared__ float ls[16];
    const int t = threadIdx.x;
    const int b = blockIdx.x >> 8;            // 4 batches x 256 row-groups
    const int R0 = (blockIdx.x & 255) << 4;   // row base within batch (16 rows)
    const int qi = (b << 6) + (R0 >> 6);      // attn q-block index
    const int ro = R0 & 63;                   // row offset inside q-block
    const float gamma = g_gamma[0];

    {
        const int r = t >> 4, cq = (t & 15) * 4;   // 16 rows x 16 c-quads
        float a0 = 0.f, a1 = 0.f, a2 = 0.f, a3 = 0.f;
#pragma unroll
        for (int s4 = 0; s4 < NSPLIT; ++s4) {
            const u16* p = O_part +
                (((size_t)qi * NSPLIT + s4) * 64 + ro + r) * 64 + cq;
            uint2 u = *reinterpret_cast<const uint2*>(p);
            a0 += bf2f((u16)(u.x & 0xFFFF));
            a1 += bf2f((u16)(u.x >> 16));
            a2 += bf2f((u16)(u.y & 0xFFFF));
            a3 += bf2f((u16)(u.y >> 16));
        }
        ot[r * 65 + cq + 0] = a0;
        ot[r * 65 + cq + 1] = a1;
        ot[r * 65 + cq + 2] = a2;
        ot[r * 65 + cq + 3] = a3;
        if (t < 16) {
            float lsum = 0.f;
#pragma unroll
            for (int s4 = 0; s4 < NSPLIT; ++s4)
                lsum += l_part[((size_t)qi * NSPLIT + s4) * 64 + ro + t];
            ls[t] = gamma / fmaxf(lsum, 1e-30f);
        }
    }
    __syncthreads();
    {
        const int c = t >> 2, nseg = t & 3;
        const size_t gbase = ((size_t)(b * 64 + c)) * 4096 + R0 + nseg * 4;
        float4 xv = *reinterpret_cast<const float4*>(&x[gbase]);
        float4 rv;
        rv.x = ot[(nseg * 4 + 0) * 65 + c] * ls[nseg * 4 + 0] + xv.x;
        rv.y = ot[(nseg * 4 + 1) * 65 + c] * ls[nseg * 4 + 1] + xv.y;
        rv.z = ot[(nseg * 4 + 2) * 65 + c] * ls[nseg * 4 + 2] + xv.z;
        rv.w = ot[(nseg * 4 + 3) * 65 + c] * ls[nseg * 4 + 3] + xv.w;
        *reinterpret_cast<float4*>(&out[gbase]) = rv;
    }
}

// ---------------------------------------------------------------- launch ---
extern "C" void kernel_launch(void* const* d_in, const int* in_sizes, int n_in,
                              void* d_out, int out_size, void* d_ws, size_t ws_size,
                              hipStream_t stream) {
    const float* x      = (const float*)d_in[0];
    const float* Wq     = (const float*)d_in[1];
    const float* bq     = (const float*)d_in[2];
    const float* Wk     = (const float*)d_in[3];
    const float* bk     = (const float*)d_in[4];
    const float* Wv     = (const float*)d_in[5];
    const float* bv     = (const float*)d_in[6];
    const float* We1    = (const float*)d_in[7];
    const float* be1    = (const float*)d_in[8];
    const float* bn_w   = (const float*)d_in[9];
    const float* bn_b   = (const float*)d_in[10];
    const float* bn_mean= (const float*)d_in[11];
    const float* bn_var = (const float*)d_in[12];
    const float* We2    = (const float*)d_in[13];
    const float* be2    = (const float*)d_in[14];
    const float* gamma  = (const float*)d_in[15];
    const float* beta   = (const float*)d_in[16];

    char* ws = (char*)d_ws;
    const size_t KB = 1024, MB = 1024 * 1024;
    u16*   Qt     = (u16*)ws;                         // [0, 2 MB)
    u16*   Kt     = (u16*)(ws + 2 * MB);              // [2, 4 MB)
    u16*   Vm     = (u16*)(ws + 4 * MB);              // [4, 6 MB)
    float* wkey   = (float*)(ws + 6 * MB);            // 64 KB
    float* l_part = (float*)(ws + 6 * MB + 64 * KB);  // up to 512 KB
    u16*   O_part = (u16*)(ws + 6 * MB + 576 * KB);   // up to 16.78 MB

    // split-8 needs 6MB + 576KB + 2048*64*64*2 = 23.66 MB of ws
    const bool use8 = ws_size >= (6 * MB + 576 * KB + (size_t)2048 * 64 * 64 * 2);

    float* out = (float*)d_out;

    qkv_edge_kernel<<<dim3(512), dim3(256), 0, stream>>>(
        x, Wq, bq, Wk, bk, Wv, bv, We1, be1, bn_w, bn_b, bn_mean, bn_var,
        We2, be2, beta, Qt, Kt, Vm, wkey);
    if (use8) {
        attn_kernel<8><<<dim3(2048), dim3(128), 0, stream>>>(Qt, Kt, Vm, wkey, O_part, l_part);
        combine_kernel<8><<<dim3(1024), dim3(256), 0, stream>>>(O_part, l_part, x, gamma, out);
    } else {
        attn_kernel<4><<<dim3(1024), dim3(128), 0, stream>>>(Qt, Kt, Vm, wkey, O_part, l_part);
        combine_kernel<4><<<dim3(1024), dim3(256), 0, stream>>>(O_part, l_part, x, gamma, out);
    }
}

// Round 7
// 152.254 us; speedup vs baseline: 1.1979x; 1.1979x over previous
//
#include <hip/hip_runtime.h>
#include <hip/hip_bf16.h>

typedef unsigned short u16;
typedef __attribute__((ext_vector_type(8))) __bf16 bf16x8;
typedef __attribute__((ext_vector_type(4))) float f32x4;

// Fragment-chunk layout for Qt/Kt/Vm (per batch, 4096x64 u16):
//   element (row n, channel c) lives at
//   ((n>>4)*8 + (c>>3))*128 + (n&15)*8 + (c&7)
// so an MFMA fragment load (lane=l15 over rows, quad over channel-octet) is
// 64 consecutive 16B chunks -> perfectly coalesced global_load_dwordx4.

__device__ __forceinline__ u16 f2bf(float f) {
    unsigned u = __builtin_bit_cast(unsigned, f);
    u += 0x7FFFu + ((u >> 16) & 1u);
    return (u16)(u >> 16);
}
__device__ __forceinline__ float bf2f(u16 v) {
    unsigned u = ((unsigned)v) << 16;
    return __builtin_bit_cast(float, u);
}

// ------------------------------------------------------------ qkv + edge ---
// grid 512:
//  bid<256:  qkv  — stage x-tile transposed + W(bf16) in LDS, 24 MFMAs,
//            write Q/K/V in fragment-chunk layout
//  bid>=256: edge — stage 3 x-rows + We1 reorder in LDS, 36 MFMAs
__global__ __launch_bounds__(256) void qkv_edge_kernel(
    const float* __restrict__ x,
    const float* __restrict__ Wq, const float* __restrict__ bq,
    const float* __restrict__ Wk, const float* __restrict__ bk,
    const float* __restrict__ Wv, const float* __restrict__ bv,
    const float* __restrict__ We1, const float* __restrict__ be1,
    const float* __restrict__ bn_w, const float* __restrict__ bn_b,
    const float* __restrict__ bn_mean, const float* __restrict__ bn_var,
    const float* __restrict__ We2, const float* __restrict__ be2,
    const float* __restrict__ beta,
    u16* __restrict__ Qt, u16* __restrict__ Kt, u16* __restrict__ Vm,
    float* __restrict__ wkey)
{
    __shared__ __align__(16) u16 sm[33280];   // 65 KB, partitioned per branch
    const int t = threadIdx.x;
    const int wv = t >> 6, lane = t & 63;
    const int quad = lane >> 4, l15 = lane & 15;

    if (blockIdx.x < 256) {
        // ---------------- qkv ----------------
        u16* Wl   = sm;                 // [3][64][72]  = 13824 u16
        u16* xt_s = sm + 13824;         // [64][66]     =  4224 u16
        u16* vt   = sm + 13824 + 4224;  // [64][72]     =  4608 u16
        const int b = blockIdx.x >> 6;
        const int n0 = (blockIdx.x & 63) << 6;

        const float* Wmat[3] = {Wq, Wk, Wv};
#pragma unroll
        for (int m = 0; m < 3; ++m)
            for (int i = 0; i < 16; ++i) {
                int lin = t + i * 256;
                Wl[(m * 64 + (lin >> 6)) * 72 + (lin & 63)] = f2bf(Wmat[m][lin]);
            }
        for (int i = 0; i < 16; ++i) {
            int lin = t + i * 256;
            int c = lin >> 6, nn = lin & 63;
            xt_s[nn * 66 + c] = f2bf(x[(size_t)(b * 64 + c) * 4096 + n0 + nn]);
        }
        __syncthreads();

        bf16x8 bx[2];
#pragma unroll
        for (int h = 0; h < 2; ++h)
            bx[h] = *reinterpret_cast<const bf16x8*>(
                &xt_s[(wv * 16 + l15) * 66 + h * 32 + quad * 8]);

        f32x4 d[3][4];
#pragma unroll
        for (int m = 0; m < 3; ++m)
#pragma unroll
            for (int mt = 0; mt < 4; ++mt) d[m][mt] = (f32x4){0.f, 0.f, 0.f, 0.f};

#pragma unroll
        for (int h = 0; h < 2; ++h)
#pragma unroll
            for (int m = 0; m < 3; ++m)
#pragma unroll
                for (int mt = 0; mt < 4; ++mt) {
                    bf16x8 af = *reinterpret_cast<const bf16x8*>(
                        &Wl[(m * 64 + mt * 16 + l15) * 72 + h * 32 + quad * 8]);
                    d[m][mt] = __builtin_amdgcn_mfma_f32_16x16x32_bf16(af, bx[h], d[m][mt], 0, 0, 0);
                }

        const float* bias[3] = {bq, bk, bv};
#pragma unroll
        for (int m = 0; m < 3; ++m)
#pragma unroll
            for (int mt = 0; mt < 4; ++mt) {
                float4 bi = *reinterpret_cast<const float4*>(bias[m] + mt * 16 + quad * 4);
                d[m][mt][0] += bi.x; d[m][mt][1] += bi.y; d[m][mt][2] += bi.z; d[m][mt][3] += bi.w;
            }

        // Q, K -> fragment-chunk layout. For thread value (row n = n0+wv*16+l15,
        // channel c = mt*16+quad*4+r): chunk = ((n0>>4)+wv)*8 + mt*2 + (quad>>1),
        // offset = l15*8 + (quad&1)*4 + r  (r=0..3 consecutive -> uint2 store)
        const int rowchunk = (n0 >> 4) + wv;
#pragma unroll
        for (int m = 0; m < 2; ++m) {
            u16* base = (m == 0 ? Qt : Kt) + (size_t)b * 262144;
#pragma unroll
            for (int mt = 0; mt < 4; ++mt) {
                uint2 pk;
                pk.x = (unsigned)f2bf(d[m][mt][0]) | ((unsigned)f2bf(d[m][mt][1]) << 16);
                pk.y = (unsigned)f2bf(d[m][mt][2]) | ((unsigned)f2bf(d[m][mt][3]) << 16);
                *reinterpret_cast<uint2*>(
                    base + ((size_t)(rowchunk * 8 + mt * 2 + (quad >> 1))) * 128 +
                    l15 * 8 + (quad & 1) * 4) = pk;
            }
        }
        // V: C-layout -> LDS [c][n_local] -> fragment-chunk global store
#pragma unroll
        for (int mt = 0; mt < 4; ++mt)
#pragma unroll
            for (int r = 0; r < 4; ++r)
                vt[(mt * 16 + quad * 4 + r) * 72 + wv * 16 + l15] = f2bf(d[2][mt][r]);
        __syncthreads();
        {
            u16* Vb_st = Vm + (size_t)b * 262144;
            const int kt = n0 >> 6;
#pragma unroll
            for (int i = 0; i < 2; ++i) {
                int unit = t + i * 256;          // 512 units = (f,hq,cl)
                int f = unit >> 7, hq = (unit >> 4) & 7, cl = unit & 15;
                const u16* src = &vt[(f * 16 + cl) * 72 + hq * 8];
                uint4 v4 = *reinterpret_cast<const uint4*>(src);
                *reinterpret_cast<uint4*>(
                    Vb_st + ((size_t)((kt * 4 + f) * 8 + hq)) * 128 + cl * 8) = v4;
            }
        }
    } else {
        // ---------------- edge ----------------
        u16* Ae_s = sm;            // [32][584]     = 18688 u16
        u16* xr_s = sm + 18688;    // [3][66][72]   = 14256 u16
        const int eb = blockIdx.x - 256;
        const int b = eb >> 6, h = eb & 63;

        if (t < 192) {
            int kh = t / 64, rem = t & 63;
            int col = (rem >> 5) * 65, ci2 = (rem & 31) * 2;
            *reinterpret_cast<unsigned*>(&xr_s[(kh * 66 + col) * 72 + ci2]) = 0u;
        }
#pragma unroll
        for (int i = 0; i < 8; ++i) {
            int pr = t + i * 256;
            int ch = pr >> 6, ci = pr & 63;
            const float* src = We1 + ch * 576 + ci * 9;
#pragma unroll
            for (int p = 0; p < 9; ++p)
                Ae_s[ch * 584 + p * 64 + ci] = f2bf(src[p]);
        }
#pragma unroll
        for (int i = 0; i < 48; ++i) {
            int e = t + i * 256;
            int kh = e >> 12, rem = e & 4095;
            int ci = rem >> 6, w = rem & 63;
            int hs = h + kh - 1;
            float v = 0.f;
            if ((unsigned)hs < 64u)
                v = x[((size_t)(b * 64 + ci) * 64 + hs) * 64 + w];
            xr_s[(kh * 66 + w + 1) * 72 + ci] = f2bf(v);
        }
        __syncthreads();

        f32x4 e[2];
        e[0] = (f32x4){0.f, 0.f, 0.f, 0.f};
        e[1] = (f32x4){0.f, 0.f, 0.f, 0.f};
#pragma unroll
        for (int p = 0; p < 9; ++p) {
            const int kh = p / 3, kw = p - kh * 3;
#pragma unroll
            for (int half = 0; half < 2; ++half) {
                bf16x8 bfr = *reinterpret_cast<const bf16x8*>(
                    &xr_s[(kh * 66 + wv * 16 + l15 + kw) * 72 + half * 32 + quad * 8]);
#pragma unroll
                for (int mt = 0; mt < 2; ++mt) {
                    bf16x8 af = *reinterpret_cast<const bf16x8*>(
                        &Ae_s[(mt * 16 + l15) * 584 + p * 64 + half * 32 + quad * 8]);
                    e[mt] = __builtin_amdgcn_mfma_f32_16x16x32_bf16(af, bfr, e[mt], 0, 0, 0);
                }
            }
        }
        float partial = 0.f;
#pragma unroll
        for (int mt = 0; mt < 2; ++mt) {
            float4 bw = *reinterpret_cast<const float4*>(bn_w    + mt * 16 + quad * 4);
            float4 bb = *reinterpret_cast<const float4*>(bn_b    + mt * 16 + quad * 4);
            float4 bm = *reinterpret_cast<const float4*>(bn_mean + mt * 16 + quad * 4);
            float4 bv2 = *reinterpret_cast<const float4*>(bn_var + mt * 16 + quad * 4);
            float4 b1 = *reinterpret_cast<const float4*>(be1     + mt * 16 + quad * 4);
            float4 w2 = *reinterpret_cast<const float4*>(We2     + mt * 16 + quad * 4);
            float sc, sh;
            sc = bw.x * rsqrtf(bv2.x + 1e-5f); sh = (b1.x - bm.x) * sc + bb.x;
            partial += fmaxf(e[mt][0] * sc + sh, 0.f) * w2.x;
            sc = bw.y * rsqrtf(bv2.y + 1e-5f); sh = (b1.y - bm.y) * sc + bb.y;
            partial += fmaxf(e[mt][1] * sc + sh, 0.f) * w2.y;
            sc = bw.z * rsqrtf(bv2.z + 1e-5f); sh = (b1.z - bm.z) * sc + bb.z;
            partial += fmaxf(e[mt][2] * sc + sh, 0.f) * w2.z;
            sc = bw.w * rsqrtf(bv2.w + 1e-5f); sh = (b1.w - bm.w) * sc + bb.w;
            partial += fmaxf(e[mt][3] * sc + sh, 0.f) * w2.w;
        }
        partial += __shfl_xor(partial, 16);
        partial += __shfl_xor(partial, 32);
        if (lane < 16) {
            float s = partial + be2[0];
            float sg = 1.f / (1.f + __expf(-s));
            wkey[(size_t)b * 4096 + h * 64 + wv * 16 + lane] = 1.f + beta[0] * sg;
        }
    }
}

// ------------------------------------------------------------- attention ---
// grid 256*NSPLIT; 128 thr = 2 waves x 32 q rows (2 independent 16-row chains).
// All Q/K/V fragment loads are coalesced 16B/lane chunks (fragment-chunk
// layout). S^T = K*Q^T, fixed-offset softmax, P via wave-local LDS,
// O += P*V^T, bf16 O_part epilogue. No barriers in k-loop.
template <int NSPLIT>
__global__ __launch_bounds__(128, 4) void attn_kernel(
    const u16* __restrict__ Qt, const u16* __restrict__ Kt,
    const u16* __restrict__ Vm, const float* __restrict__ wkey,
    u16* __restrict__ O_part, float* __restrict__ l_part)
{
    constexpr int KT_ITERS = 64 / NSPLIT;
    __shared__ __align__(16) u16 p_s_all[2 * 32 * 68];
    const int t = threadIdx.x;
    const int qi = blockIdx.x / NSPLIT;        // 0..255 (64-row q block)
    const int split = blockIdx.x % NSPLIT;
    const int b = qi >> 6;
    const int n0 = (qi & 63) << 6;
    const int wv = t >> 6, lane = t & 63;
    const int quad = lane >> 4, l15 = lane & 15;
    u16* p_s = p_s_all + wv * (32 * 68);

    const u16* Qb = Qt + (size_t)b * 262144;
    const u16* Kb = Kt + (size_t)b * 262144;
    const u16* Vb = Vm + (size_t)b * 262144;
    const float* wb = wkey + (size_t)b * 4096;

    bf16x8 qf[2][2];
#pragma unroll
    for (int nt = 0; nt < 2; ++nt)
#pragma unroll
        for (int h = 0; h < 2; ++h)
            qf[nt][h] = __builtin_bit_cast(bf16x8, *reinterpret_cast<const uint4*>(
                Qb + ((size_t)(((n0 >> 4) + wv * 2 + nt) * 8 + h * 4 + quad)) * 128 + l15 * 8));

    const int kt0 = split * KT_ITERS;
    uint4 kf[4][2];
    float4 wf[4];
#pragma unroll
    for (int mt = 0; mt < 4; ++mt) {
#pragma unroll
        for (int h = 0; h < 2; ++h)
            kf[mt][h] = *reinterpret_cast<const uint4*>(
                Kb + ((size_t)((kt0 * 4 + mt) * 8 + h * 4 + quad)) * 128 + l15 * 8);
        wf[mt] = *reinterpret_cast<const float4*>(wb + kt0 * 64 + mt * 16 + quad * 4);
    }

    f32x4 o[2][4];
#pragma unroll
    for (int m2 = 0; m2 < 2; ++m2)
#pragma unroll
        for (int f = 0; f < 4; ++f) o[m2][f] = (f32x4){0.f, 0.f, 0.f, 0.f};
    float l_acc[2] = {0.f, 0.f};

    for (int kt = kt0; kt < kt0 + KT_ITERS; ++kt) {
        uint4 vf[4][2];
#pragma unroll
        for (int f = 0; f < 4; ++f)
#pragma unroll
            for (int h = 0; h < 2; ++h)
                vf[f][h] = *reinterpret_cast<const uint4*>(
                    Vb + ((size_t)((kt * 4 + f) * 8 + h * 4 + quad)) * 128 + l15 * 8);

        f32x4 s[4][2];
#pragma unroll
        for (int mt = 0; mt < 4; ++mt)
#pragma unroll
            for (int nt = 0; nt < 2; ++nt) {
                f32x4 a = (f32x4){0.f, 0.f, 0.f, 0.f};
                a = __builtin_amdgcn_mfma_f32_16x16x32_bf16(
                        __builtin_bit_cast(bf16x8, kf[mt][0]), qf[nt][0], a, 0, 0, 0);
                a = __builtin_amdgcn_mfma_f32_16x16x32_bf16(
                        __builtin_bit_cast(bf16x8, kf[mt][1]), qf[nt][1], a, 0, 0, 0);
                s[mt][nt] = a;
            }

        const int ktn = (kt + 1 < kt0 + KT_ITERS) ? kt + 1 : kt0;
#pragma unroll
        for (int mt = 0; mt < 4; ++mt)
#pragma unroll
            for (int h = 0; h < 2; ++h)
                kf[mt][h] = *reinterpret_cast<const uint4*>(
                    Kb + ((size_t)((ktn * 4 + mt) * 8 + h * 4 + quad)) * 128 + l15 * 8);

#pragma unroll
        for (int mt = 0; mt < 4; ++mt)
#pragma unroll
            for (int nt = 0; nt < 2; ++nt) {
                u16 pk[4];
#pragma unroll
                for (int r = 0; r < 4; ++r) {
                    float p = __expf(s[mt][nt][r] - 12.0f) *
                              reinterpret_cast<const float*>(&wf[mt])[r];
                    l_acc[nt] += p;
                    pk[r] = f2bf(p);
                }
                uint2 packed;
                packed.x = (unsigned)pk[0] | ((unsigned)pk[1] << 16);
                packed.y = (unsigned)pk[2] | ((unsigned)pk[3] << 16);
                *reinterpret_cast<uint2*>(
                    &p_s[(nt * 16 + l15) * 68 + mt * 16 + quad * 4]) = packed;
            }

#pragma unroll
        for (int mt = 0; mt < 4; ++mt)
            wf[mt] = *reinterpret_cast<const float4*>(wb + ktn * 64 + mt * 16 + quad * 4);

        bf16x8 pa[2][2];
#pragma unroll
        for (int m2 = 0; m2 < 2; ++m2)
#pragma unroll
            for (int h = 0; h < 2; ++h) {
                uint2 lo = *reinterpret_cast<const uint2*>(
                    &p_s[(m2 * 16 + l15) * 68 + h * 32 + quad * 8]);
                uint2 hi = *reinterpret_cast<const uint2*>(
                    &p_s[(m2 * 16 + l15) * 68 + h * 32 + quad * 8 + 4]);
                uint4 c4; c4.x = lo.x; c4.y = lo.y; c4.z = hi.x; c4.w = hi.y;
                pa[m2][h] = __builtin_bit_cast(bf16x8, c4);
            }

#pragma unroll
        for (int m2 = 0; m2 < 2; ++m2)
#pragma unroll
            for (int f = 0; f < 4; ++f) {
                o[m2][f] = __builtin_amdgcn_mfma_f32_16x16x32_bf16(
                    pa[m2][0], __builtin_bit_cast(bf16x8, vf[f][0]), o[m2][f], 0, 0, 0);
                o[m2][f] = __builtin_amdgcn_mfma_f32_16x16x32_bf16(
                    pa[m2][1], __builtin_bit_cast(bf16x8, vf[f][1]), o[m2][f], 0, 0, 0);
            }
    }

    const size_t pbase = (size_t)blockIdx.x * 64;
#pragma unroll
    for (int nt = 0; nt < 2; ++nt) {
        float v = l_acc[nt];
        v += __shfl_xor(v, 16);
        v += __shfl_xor(v, 32);
        if (lane < 16) l_part[pbase + wv * 32 + nt * 16 + lane] = v;
    }
#pragma unroll
    for (int m2 = 0; m2 < 2; ++m2)
#pragma unroll
        for (int f = 0; f < 4; ++f)
#pragma unroll
            for (int r = 0; r < 4; ++r)
                O_part[(pbase + wv * 32 + m2 * 16 + quad * 4 + r) * 64 + f * 16 + l15] =
                    f2bf(o[m2][f][r]);
}

// ---------------------------------------------------------------- combine --
// grid 1024: 16 q-rows per block. Sum NSPLIT partials, normalize,
// gamma*O + x, transpose (n,c)->(c,n).
template <int NSPLIT>
__global__ __launch_bounds__(256) void combine_kernel(
    const u16* __restrict__ O_part, const float* __restrict__ l_part,
    const float* __restrict__ x, const float* __restrict__ g_gamma,
    float* __restrict__ out)
{
    __shared__ float ot[16 * 65];
    __shared__ float ls[16];
    const int t = threadIdx.x;
    const int b = blockIdx.x >> 8;
    const int R0 = (blockIdx.x & 255) << 4;
    const int qi = (b << 6) + (R0 >> 6);
    const int ro = R0 & 63;
    const float gamma = g_gamma[0];

    {
        const int r = t >> 4, cq = (t & 15) * 4;
        float a0 = 0.f, a1 = 0.f, a2 = 0.f, a3 = 0.f;
#pragma unroll
        for (int s4 = 0; s4 < NSPLIT; ++s4) {
            const u16* p = O_part +
                (((size_t)qi * NSPLIT + s4) * 64 + ro + r) * 64 + cq;
            uint2 u = *reinterpret_cast<const uint2*>(p);
            a0 += bf2f((u16)(u.x & 0xFFFF));
            a1 += bf2f((u16)(u.x >> 16));
            a2 += bf2f((u16)(u.y & 0xFFFF));
            a3 += bf2f((u16)(u.y >> 16));
        }
        ot[r * 65 + cq + 0] = a0;
        ot[r * 65 + cq + 1] = a1;
        ot[r * 65 + cq + 2] = a2;
        ot[r * 65 + cq + 3] = a3;
        if (t < 16) {
            float lsum = 0.f;
#pragma unroll
            for (int s4 = 0; s4 < NSPLIT; ++s4)
                lsum += l_part[((size_t)qi * NSPLIT + s4) * 64 + ro + t];
            ls[t] = gamma / fmaxf(lsum, 1e-30f);
        }
    }
    __syncthreads();
    {
        const int c = t >> 2, nseg = t & 3;
        const size_t gbase = ((size_t)(b * 64 + c)) * 4096 + R0 + nseg * 4;
        float4 xv = *reinterpret_cast<const float4*>(&x[gbase]);
        float4 rv;
        rv.x = ot[(nseg * 4 + 0) * 65 + c] * ls[nseg * 4 + 0] + xv.x;
        rv.y = ot[(nseg * 4 + 1) * 65 + c] * ls[nseg * 4 + 1] + xv.y;
        rv.z = ot[(nseg * 4 + 2) * 65 + c] * ls[nseg * 4 + 2] + xv.z;
        rv.w = ot[(nseg * 4 + 3) * 65 + c] * ls[nseg * 4 + 3] + xv.w;
        *reinterpret_cast<float4*>(&out[gbase]) = rv;
    }
}

// ---------------------------------------------------------------- launch ---
extern "C" void kernel_launch(void* const* d_in, const int* in_sizes, int n_in,
                              void* d_out, int out_size, void* d_ws, size_t ws_size,
                              hipStream_t stream) {
    const float* x      = (const float*)d_in[0];
    const float* Wq     = (const float*)d_in[1];
    const float* bq     = (const float*)d_in[2];
    const float* Wk     = (const float*)d_in[3];
    const float* bk     = (const float*)d_in[4];
    const float* Wv     = (const float*)d_in[5];
    const float* bv     = (const float*)d_in[6];
    const float* We1    = (const float*)d_in[7];
    const float* be1    = (const float*)d_in[8];
    const float* bn_w   = (const float*)d_in[9];
    const float* bn_b   = (const float*)d_in[10];
    const float* bn_mean= (const float*)d_in[11];
    const float* bn_var = (const float*)d_in[12];
    const float* We2    = (const float*)d_in[13];
    const float* be2    = (const float*)d_in[14];
    const float* gamma  = (const float*)d_in[15];
    const float* beta   = (const float*)d_in[16];

    char* ws = (char*)d_ws;
    const size_t KB = 1024, MB = 1024 * 1024;
    u16*   Qt     = (u16*)ws;                         // [0, 2 MB)
    u16*   Kt     = (u16*)(ws + 2 * MB);              // [2, 4 MB)
    u16*   Vm     = (u16*)(ws + 4 * MB);              // [4, 6 MB)
    float* wkey   = (float*)(ws + 6 * MB);            // 64 KB
    float* l_part = (float*)(ws + 6 * MB + 64 * KB);  // up to 512 KB
    u16*   O_part = (u16*)(ws + 6 * MB + 576 * KB);   // up to 16.78 MB

    const bool use8 = ws_size >= (6 * MB + 576 * KB + (size_t)2048 * 64 * 64 * 2);

    float* out = (float*)d_out;

    qkv_edge_kernel<<<dim3(512), dim3(256), 0, stream>>>(
        x, Wq, bq, Wk, bk, Wv, bv, We1, be1, bn_w, bn_b, bn_mean, bn_var,
        We2, be2, beta, Qt, Kt, Vm, wkey);
    if (use8) {
        attn_kernel<8><<<dim3(2048), dim3(128), 0, stream>>>(Qt, Kt, Vm, wkey, O_part, l_part);
        combine_kernel<8><<<dim3(1024), dim3(256), 0, stream>>>(O_part, l_part, x, gamma, out);
    } else {
        attn_kernel<4><<<dim3(1024), dim3(128), 0, stream>>>(Qt, Kt, Vm, wkey, O_part, l_part);
        combine_kernel<4><<<dim3(1024), dim3(256), 0, stream>>>(O_part, l_part, x, gamma, out);
    }
}